// Round 3
// 41165.671 us; speedup vs baseline: 1.0377x; 1.0377x over previous
//
#include <hip/hip_runtime.h>

#define B_ 32
#define T_ 512
#define H_ 1024
#define TOK_ 26
#define EMB_ 512
#define OUT_ 26
#define BH_ (B_ * H_)
#define NBTH_ ((size_t)B_ * T_ * H_)

// ---------------- kernel 1: fuse embed weights ----------------
__global__ void k_fuse_w(const float* __restrict__ W_emb, const float* __restrict__ W_tok,
                         const float* __restrict__ W_coord, float* __restrict__ Wt,
                         float* __restrict__ Wc) {
    int idx = blockIdx.x * 256 + threadIdx.x;
    if (idx >= 2 * H_ * TOK_) return;
    int which = idx >= H_ * TOK_;
    int rem = idx - which * (H_ * TOK_);
    int h = rem / TOK_;
    int k = rem - h * TOK_;
    const float* Wsel = which ? W_coord : W_tok;
    const float* we = W_emb + (size_t)h * EMB_ + which * 256;
    float acc = 0.f;
#pragma unroll 8
    for (int e = 0; e < 256; ++e) acc += we[e] * Wsel[e * TOK_ + k];
    (which ? Wc : Wt)[h * TOK_ + k] = acc;
}

// ---------------- kernel 2: fused embed ----------------
__global__ void k_embed(const float* __restrict__ t_in, const float* __restrict__ c_in,
                        const float* __restrict__ Wt, const float* __restrict__ Wc,
                        const float* __restrict__ b_emb, float* __restrict__ emb) {
    int row = blockIdx.x;  // b*T_ + t
    int tid = threadIdx.x;
    __shared__ float tv[TOK_], cv[TOK_];
    if (tid < TOK_) tv[tid] = t_in[(size_t)row * TOK_ + tid];
    else if (tid < 2 * TOK_) cv[tid - TOK_] = c_in[(size_t)row * TOK_ + (tid - TOK_)];
    __syncthreads();
#pragma unroll
    for (int i = 0; i < 4; ++i) {
        int h = tid + i * 256;
        float acc = b_emb[h];
        const float* wt = Wt + h * TOK_;
        const float* wc = Wc + h * TOK_;
#pragma unroll
        for (int k = 0; k < TOK_; ++k) acc += tv[k] * wt[k] + cv[k] * wc[k];
        emb[(size_t)row * H_ + h] = fmaxf(acc, 0.f);
    }
}

// ---------------- kernel 3: I0 = emb @ W_ih[0]^T + b_ih[0] ----------------
__global__ __launch_bounds__(256) void k_i0(const float* __restrict__ A,
                                            const float* __restrict__ W,
                                            const float* __restrict__ bias,
                                            float* __restrict__ p0, float* __restrict__ p1,
                                            float* __restrict__ p2) {
    __shared__ float As[32][132];
    __shared__ float Bs[32][132];
    int tid = threadIdx.x;
    int m0 = blockIdx.x * 128, n0 = blockIdx.y * 128;
    int ty = tid >> 4, tx = tid & 15;
    float acc[8][8] = {};
    for (int k0 = 0; k0 < 1024; k0 += 32) {
#pragma unroll
        for (int p = 0; p < 4; ++p) {
            int idx = tid + p * 256;
            int r = idx >> 3, c = idx & 7;
            float4 va = *(const float4*)(A + (size_t)(m0 + r) * 1024 + k0 + c * 4);
            float4 vb = *(const float4*)(W + (size_t)(n0 + r) * 1024 + k0 + c * 4);
            As[c * 4 + 0][r] = va.x; As[c * 4 + 1][r] = va.y;
            As[c * 4 + 2][r] = va.z; As[c * 4 + 3][r] = va.w;
            Bs[c * 4 + 0][r] = vb.x; Bs[c * 4 + 1][r] = vb.y;
            Bs[c * 4 + 2][r] = vb.z; Bs[c * 4 + 3][r] = vb.w;
        }
        __syncthreads();
#pragma unroll 8
        for (int kk = 0; kk < 32; ++kk) {
            float af[8], bf[8];
#pragma unroll
            for (int i = 0; i < 8; ++i) af[i] = As[kk][ty * 8 + i];
#pragma unroll
            for (int i = 0; i < 8; ++i) bf[i] = Bs[kk][tx * 8 + i];
#pragma unroll
            for (int i = 0; i < 8; ++i)
#pragma unroll
                for (int j = 0; j < 8; ++j) acc[i][j] += af[i] * bf[j];
        }
        __syncthreads();
    }
    int g = n0 >> 10;
    float* plane = g == 0 ? p0 : (g == 1 ? p1 : p2);
    int dbase = (n0 & 1023) + tx * 8;
    float bs[8];
#pragma unroll
    for (int j = 0; j < 8; ++j) bs[j] = bias[n0 + tx * 8 + j];
#pragma unroll
    for (int i = 0; i < 8; ++i) {
        int m = m0 + ty * 8 + i;
#pragma unroll
        for (int j = 0; j < 8; ++j)
            plane[(size_t)m * 1024 + dbase + j] = acc[i][j] + bs[j];
    }
}

// ---------------- software grid barrier (device-scope, timeout-protected) ----------------
__device__ __forceinline__ void grid_barrier(unsigned* cnt, unsigned* gen, unsigned nblk) {
    __syncthreads();
    if (threadIdx.x == 0) {
        __threadfence();  // release this block's prior writes device-wide
        unsigned g = __hip_atomic_load(gen, __ATOMIC_RELAXED, __HIP_MEMORY_SCOPE_AGENT);
        unsigned arrived =
            __hip_atomic_fetch_add(cnt, 1u, __ATOMIC_ACQ_REL, __HIP_MEMORY_SCOPE_AGENT);
        if (arrived == nblk - 1) {
            __hip_atomic_store(cnt, 0u, __ATOMIC_RELAXED, __HIP_MEMORY_SCOPE_AGENT);
            __hip_atomic_store(gen, g + 1u, __ATOMIC_RELEASE, __HIP_MEMORY_SCOPE_AGENT);
        } else {
            long long t0 = __builtin_amdgcn_s_memrealtime();
            while (__hip_atomic_load(gen, __ATOMIC_ACQUIRE, __HIP_MEMORY_SCOPE_AGENT) == g) {
                __builtin_amdgcn_s_sleep(8);
                // ~1 s at the 100 MHz realtime clock: bail instead of hanging the GPU
                if (__builtin_amdgcn_s_memrealtime() - t0 > 100000000LL) break;
            }
        }
        __threadfence();  // acquire: invalidate stale cached lines before plain loads
    }
    __syncthreads();
}

// ---------------- kernel 4: persistent GRU (plain launch + software barrier) ----------------
// 256 WGs x 512 thr, 1 WG/CU (148.5 KB LDS). WG bid owns layer-0 dims bid*4+j AND
// layer-1 dims bid*4+j. LDS rows: 0-11 = L0 W_hh (h0), 12-23 = L1 W_ih (x = h0),
// 24-35 = L1 W_hh (h1). Waves 0-3 (tid<256): L0 dots (6 rows x 8 batches x 32-k each).
// Waves 4-7: L1 dots (12 rows x 8 batches x 32-k; rg0 -> ih rows/h0, rg1 -> hh rows/h1).
// Diagonal wavefront: phase s = layer0 step s + layer1 step s-1; ONE barrier per phase.
__global__ __launch_bounds__(512, 2) void k_gru_persist(
    const float* __restrict__ i0r, const float* __restrict__ i0z, const float* __restrict__ i0n,
    const float* __restrict__ W_ih, const float* __restrict__ W_hh,
    const float* __restrict__ b_ih, const float* __restrict__ b_hh,
    float* __restrict__ hbuf,
    float* __restrict__ o_acts, float* __restrict__ o_z,
    float* __restrict__ o_r, float* __restrict__ o_n,
    unsigned* __restrict__ bar) {
    __shared__ float lw[36][1024];   // 144 KB
    __shared__ float sums[36][32];   // 4.5 KB
    int bid = blockIdx.x;
    int tid = threadIdx.x;
    unsigned* bcnt = bar;
    unsigned* bgen = bar + 1;

    // ---- load this WG's 36 weight rows into LDS (once) ----
    {
        const float* W1i = W_ih + (size_t)3 * H_ * H_;
        const float* W1h = W_hh + (size_t)3 * H_ * H_;
        for (int idx = tid; idx < 36 * 256; idx += 512) {
            int r = idx >> 8, c4 = (idx & 255) << 2;
            const float* src;
            if (r < 12) {
                src = W_hh + ((size_t)(r >> 2) * H_ + bid * 4 + (r & 3)) * H_;
            } else if (r < 24) {
                int rr = r - 12;
                src = W1i + ((size_t)(rr >> 2) * H_ + bid * 4 + (rr & 3)) * H_;
            } else {
                int rr = r - 24;
                src = W1h + ((size_t)(rr >> 2) * H_ + bid * 4 + (rr & 3)) * H_;
            }
            *(float4*)&lw[r][c4] = *(const float4*)(src + c4);
        }
    }

    int grp = tid >> 8;            // 0 = layer-0 waves, 1 = layer-1 waves
    int u = tid & 255;
    int ks = u & 31, bg = (u >> 5) & 3, rg = u >> 7;
    int qj = tid & 3, qb = (tid >> 2) & 31, qd = bid * 4 + (tid & 3);

    float bA_r = 0, bA_z = 0, bA_n = 0;
    float bB_ir = 0, bB_iz = 0, bB_in = 0, bB_hr = 0, bB_hz = 0, bB_hn = 0;
    if (grp == 0) {
        if (tid < 128) {
            bA_r = b_hh[qd]; bA_z = b_hh[H_ + qd]; bA_n = b_hh[2 * H_ + qd];
        }
    } else if (tid < 384) {
        const float* bi1 = b_ih + 3 * H_;
        const float* bh1 = b_hh + 3 * H_;
        bB_ir = bi1[qd]; bB_iz = bi1[H_ + qd]; bB_in = bi1[2 * H_ + qd];
        bB_hr = bh1[qd]; bB_hz = bh1[H_ + qd]; bB_hn = bh1[2 * H_ + qd];
    }
    __syncthreads();

    for (int s = 0; s <= T_; ++s) {
        int par = s & 1;
        const float* h0p = hbuf + (par * 2 + 0) * BH_;
        const float* h1p = hbuf + (par * 2 + 1) * BH_;
        float* h0n_ = hbuf + ((par ^ 1) * 2 + 0) * BH_;
        float* h1n_ = hbuf + ((par ^ 1) * 2 + 1) * BH_;

        // prefetch gate inputs (hidden under the dot loop)
        float pir = 0, piz = 0, pin = 0, php = 0;
        if (grp == 0) {
            if (tid < 128 && s < T_) {
                size_t o = ((size_t)qb * T_ + s) * H_ + qd;
                pir = i0r[o]; piz = i0z[o]; pin = i0n[o];
                php = h0p[qb * H_ + qd];
            }
        } else {
            if (tid < 384 && s >= 1) php = h1p[qb * H_ + qd];
        }

        if (grp == 0) {
            // ---- layer-0 dots: rows rg*6 .. rg*6+5, all h0-sourced ----
            const float* hb = h0p + (size_t)(bg * 8) * H_ + ks * 4;
            const float* wb = &lw[rg * 6][0] + ks * 4;
            float acc[6][8];
#pragma unroll
            for (int i = 0; i < 6; ++i)
#pragma unroll
                for (int b2 = 0; b2 < 8; ++b2) acc[i][b2] = 0.f;
#pragma unroll 2
            for (int kq = 0; kq < 8; ++kq) {
                float4 hh[8];
#pragma unroll
                for (int b2 = 0; b2 < 8; ++b2)
                    hh[b2] = *(const float4*)(hb + (size_t)b2 * H_ + kq * 128);
#pragma unroll
                for (int i = 0; i < 6; ++i) {
                    float4 wv = *(const float4*)(wb + i * 1024 + kq * 128);
#pragma unroll
                    for (int b2 = 0; b2 < 8; ++b2)
                        acc[i][b2] += wv.x * hh[b2].x + wv.y * hh[b2].y +
                                      wv.z * hh[b2].z + wv.w * hh[b2].w;
                }
            }
#pragma unroll
            for (int i = 0; i < 6; ++i)
#pragma unroll
                for (int b2 = 0; b2 < 8; ++b2) {
                    float v = acc[i][b2];
                    v += __shfl_xor(v, 1);  v += __shfl_xor(v, 2);
                    v += __shfl_xor(v, 4);  v += __shfl_xor(v, 8);
                    v += __shfl_xor(v, 16);
                    if (ks == 0) sums[rg * 6 + i][bg * 8 + b2] = v;
                }
        } else {
            // ---- layer-1 dots: rg0 -> rows 12-23 (ih, h0), rg1 -> rows 24-35 (hh, h1) ----
            const float* hsrc = rg ? h1p : h0p;
            int R0 = 12 + rg * 12;
            const float* hb = hsrc + (size_t)(bg * 8) * H_ + ks * 4;
            const float* wb = &lw[R0][0] + ks * 4;
            float acc[12][8];
#pragma unroll
            for (int i = 0; i < 12; ++i)
#pragma unroll
                for (int b2 = 0; b2 < 8; ++b2) acc[i][b2] = 0.f;
#pragma unroll 2
            for (int kq = 0; kq < 8; ++kq) {
                float4 hh[8];
#pragma unroll
                for (int b2 = 0; b2 < 8; ++b2)
                    hh[b2] = *(const float4*)(hb + (size_t)b2 * H_ + kq * 128);
#pragma unroll
                for (int i = 0; i < 12; ++i) {
                    float4 wv = *(const float4*)(wb + i * 1024 + kq * 128);
#pragma unroll
                    for (int b2 = 0; b2 < 8; ++b2)
                        acc[i][b2] += wv.x * hh[b2].x + wv.y * hh[b2].y +
                                      wv.z * hh[b2].z + wv.w * hh[b2].w;
                }
            }
#pragma unroll
            for (int i = 0; i < 12; ++i)
#pragma unroll
                for (int b2 = 0; b2 < 8; ++b2) {
                    float v = acc[i][b2];
                    v += __shfl_xor(v, 1);  v += __shfl_xor(v, 2);
                    v += __shfl_xor(v, 4);  v += __shfl_xor(v, 8);
                    v += __shfl_xor(v, 16);
                    if (ks == 0) sums[R0 + i][bg * 8 + b2] = v;
                }
        }
        __syncthreads();

        // ---- gates ----
        if (grp == 0) {
            if (tid < 128 && s < T_) {
                float hr = sums[qj][qb], hz = sums[4 + qj][qb], hn = sums[8 + qj][qb];
                float r = 1.f / (1.f + expf(-(pir + hr + bA_r)));
                float z = 1.f / (1.f + expf(-(piz + hz + bA_z)));
                float n = tanhf(pin + r * (hn + bA_n));
                float hnew = n + z * (php - n);
                h0n_[qb * H_ + qd] = hnew;
                size_t oo = ((size_t)qb * T_ + s) * H_ + qd;
                o_acts[oo] = hnew; o_z[oo] = z; o_r[oo] = r; o_n[oo] = n;
            }
        } else {
            if (tid < 384 && s >= 1) {
                int t2 = s - 1;
                float ir = sums[12 + qj][qb] + bB_ir;
                float iz = sums[16 + qj][qb] + bB_iz;
                float in_ = sums[20 + qj][qb] + bB_in;
                float hr = sums[24 + qj][qb] + bB_hr;
                float hz = sums[28 + qj][qb] + bB_hz;
                float hn = sums[32 + qj][qb] + bB_hn;
                float r = 1.f / (1.f + expf(-(ir + hr)));
                float z = 1.f / (1.f + expf(-(iz + hz)));
                float n = tanhf(in_ + r * hn);
                float hnew = n + z * (php - n);
                h1n_[qb * H_ + qd] = hnew;
                size_t oo = NBTH_ + ((size_t)qb * T_ + t2) * H_ + qd;
                o_acts[oo] = hnew; o_z[oo] = z; o_r[oo] = r; o_n[oo] = n;
            }
        }
        if (s < T_) grid_barrier(bcnt, bgen, 256u);  // no barrier needed after final phase
    }
}

// ---------------- kernel 5: LayerNorm row stats ----------------
__global__ void k_lnstats(const float* __restrict__ top, float* __restrict__ stats) {
    int row = blockIdx.x;
    int tid = threadIdx.x;
    float4 v = *(const float4*)(top + (size_t)row * H_ + tid * 4);
    float s = v.x + v.y + v.z + v.w;
    float ss = v.x * v.x + v.y * v.y + v.z * v.z + v.w * v.w;
    for (int off = 32; off; off >>= 1) {
        s += __shfl_down(s, off, 64);
        ss += __shfl_down(ss, off, 64);
    }
    __shared__ float sb[4], ssb[4];
    int w = tid >> 6;
    if ((tid & 63) == 0) { sb[w] = s; ssb[w] = ss; }
    __syncthreads();
    if (tid == 0) {
        float S = sb[0] + sb[1] + sb[2] + sb[3];
        float SS = ssb[0] + ssb[1] + ssb[2] + ssb[3];
        float mu = S * (1.f / H_);
        float var = SS * (1.f / H_) - mu * mu;
        stats[row * 2] = mu;
        stats[row * 2 + 1] = rsqrtf(var + 1e-5f);
    }
}

// ---------------- kernel 6: fc = relu(LN(top) @ W_fc.T) ----------------
__global__ __launch_bounds__(256) void k_fc(const float* __restrict__ top,
                                            const float* __restrict__ stats,
                                            const float* __restrict__ gamma,
                                            const float* __restrict__ beta,
                                            const float* __restrict__ W_fc,
                                            float* __restrict__ fc_out) {
    __shared__ float At[64][17];
    __shared__ float Bt[64][17];
    __shared__ float mu_s[64], rs_s[64];
    int tid = threadIdx.x;
    int m0 = blockIdx.x * 64;
    int j0 = blockIdx.y * 64;
    if (tid < 64) {
        mu_s[tid] = stats[(size_t)(m0 + tid) * 2];
        rs_s[tid] = stats[(size_t)(m0 + tid) * 2 + 1];
    }
    __syncthreads();
    int ty = tid >> 4, tx = tid & 15;
    float acc[4][4] = {};
    for (int kt = 0; kt < H_; kt += 16) {
#pragma unroll
        for (int i = 0; i < 4; ++i) {
            int idx = tid + i * 256;
            int r = idx >> 4, k = idx & 15;
            float raw = top[(size_t)(m0 + r) * H_ + kt + k];
            At[r][k] = (raw - mu_s[r]) * rs_s[r] * gamma[kt + k] + beta[kt + k];
            Bt[r][k] = W_fc[(size_t)(j0 + r) * H_ + kt + k];
        }
        __syncthreads();
#pragma unroll
        for (int k = 0; k < 16; ++k) {
            float a0 = At[ty * 4 + 0][k], a1 = At[ty * 4 + 1][k];
            float a2 = At[ty * 4 + 2][k], a3 = At[ty * 4 + 3][k];
            float b0 = Bt[tx * 4 + 0][k], b1 = Bt[tx * 4 + 1][k];
            float b2 = Bt[tx * 4 + 2][k], b3 = Bt[tx * 4 + 3][k];
            acc[0][0] += a0 * b0; acc[0][1] += a0 * b1; acc[0][2] += a0 * b2; acc[0][3] += a0 * b3;
            acc[1][0] += a1 * b0; acc[1][1] += a1 * b1; acc[1][2] += a1 * b2; acc[1][3] += a1 * b3;
            acc[2][0] += a2 * b0; acc[2][1] += a2 * b1; acc[2][2] += a2 * b2; acc[2][3] += a2 * b3;
            acc[3][0] += a3 * b0; acc[3][1] += a3 * b1; acc[3][2] += a3 * b2; acc[3][3] += a3 * b3;
        }
        __syncthreads();
    }
#pragma unroll
    for (int i = 0; i < 4; ++i)
#pragma unroll
        for (int j = 0; j < 4; ++j)
            fc_out[(size_t)(m0 + ty * 4 + i) * H_ + j0 + tx * 4 + j] = fmaxf(acc[i][j], 0.f);
}

// ---------------- kernel 7: readout ----------------
__global__ void k_ro(const float* __restrict__ fc_out, const float* __restrict__ W_ro,
                     float* __restrict__ out) {
    int row = blockIdx.x;
    int tid = threadIdx.x;
    __shared__ float xrow[H_];
    *(float4*)&xrow[tid * 4] = *(const float4*)(fc_out + (size_t)row * H_ + tid * 4);
    __syncthreads();
    int o = tid >> 3, ks = tid & 7;
    float acc = 0.f;
    if (o < OUT_) {
        const float* w = W_ro + (size_t)o * H_ + ks * 128;
        const float* xs = xrow + ks * 128;
#pragma unroll 16
        for (int k = 0; k < 128; ++k) {
            int idx = (k + 4 * ks) & 127;
            acc += xs[idx] * w[idx];
        }
    }
    __shared__ float red[OUT_][8];
    if (o < OUT_) red[o][ks] = acc;
    __syncthreads();
    if (tid < OUT_) {
        float s = 0.f;
#pragma unroll
        for (int i = 0; i < 8; ++i) s += red[tid][i];
        out[(size_t)row * OUT_ + tid] = s;
    }
}

extern "C" void kernel_launch(void* const* d_in, const int* in_sizes, int n_in,
                              void* d_out, int out_size, void* d_ws, size_t ws_size,
                              hipStream_t stream) {
    (void)in_sizes; (void)n_in; (void)out_size; (void)ws_size;
    const float* t_in    = (const float*)d_in[0];
    const float* c_in    = (const float*)d_in[1];
    const float* W_tok   = (const float*)d_in[2];
    const float* W_coord = (const float*)d_in[3];
    const float* W_emb   = (const float*)d_in[4];
    const float* b_emb   = (const float*)d_in[5];
    const float* W_ih    = (const float*)d_in[6];
    const float* W_hh    = (const float*)d_in[7];
    const float* b_ih    = (const float*)d_in[8];
    const float* b_hh    = (const float*)d_in[9];
    const float* gamma   = (const float*)d_in[10];
    const float* beta    = (const float*)d_in[11];
    const float* W_fc    = (const float*)d_in[12];
    const float* W_ro    = (const float*)d_in[13];

    float* out = (float*)d_out;
    const size_t NOUT0 = (size_t)B_ * T_ * OUT_;
    const size_t NBTH  = (size_t)B_ * T_ * H_;
    const size_t NLBTH = 2 * NBTH;
    float* o_acts = out + NOUT0;
    float* o_z = o_acts + NLBTH;
    float* o_r = o_z + NLBTH;
    float* o_n = o_r + NLBTH;

    float* ws = (float*)d_ws;
    float* fc_out = ws;                    // 64 MB; doubles as emb (dead before k_fc)
    float* emb    = ws;
    float* stats  = ws + 16777216;
    float* hbuf   = stats + 32768;         // 4 * B*H: h[parity][layer]
    float* Wt     = hbuf + 4 * B_ * H_;
    float* Wc     = Wt + H_ * TOK_;
    unsigned* bar = (unsigned*)(Wc + H_ * TOK_);   // [cnt, gen]

    // I0 gate planes overlay layer-1 z/r/n output regions:
    // phase s reads I0 row t=s while layer-1 gates write row t=s-1 -> disjoint.
    float* i0r = o_z + NBTH;
    float* i0z = o_r + NBTH;
    float* i0n = o_n + NBTH;

    hipMemsetAsync(hbuf, 0, (size_t)4 * B_ * H_ * sizeof(float), stream);
    hipMemsetAsync(bar, 0, 2 * sizeof(unsigned), stream);

    k_fuse_w<<<(2 * H_ * TOK_ + 255) / 256, 256, 0, stream>>>(W_emb, W_tok, W_coord, Wt, Wc);
    k_embed<<<B_ * T_, 256, 0, stream>>>(t_in, c_in, Wt, Wc, b_emb, emb);
    k_i0<<<dim3(128, 24), 256, 0, stream>>>(emb, W_ih, b_ih, i0r, i0z, i0n);

    k_gru_persist<<<256, 512, 0, stream>>>(i0r, i0z, i0n, W_ih, W_hh, b_ih, b_hh,
                                           hbuf, o_acts, o_z, o_r, o_n, bar);

    k_lnstats<<<B_ * T_, 256, 0, stream>>>(o_acts + NBTH, stats);
    k_fc<<<dim3((B_ * T_) / 64, H_ / 64), 256, 0, stream>>>(o_acts + NBTH, stats, gamma, beta,
                                                            W_fc, fc_out);
    k_ro<<<B_ * T_, 256, 0, stream>>>(fc_out, W_ro, out);
}